// Round 1
// baseline (679.142 us; speedup 1.0000x reference)
//
#include <hip/hip_runtime.h>

#define NN 50000
#define NE 250000
#define ND 32
#define ED 16
#define NH 32

// ---------------------------------------------------------------------------
// pack w2 (32 x 1024 f32, layout [k][d*32+hid]) into bf16 hid-pairs:
// w2pk[k*512 + d*16 + p] = (bf16(w2[k][d*32+2p+1]) << 16) | bf16(w2[k][d*32+2p])
// ---------------------------------------------------------------------------
__device__ __forceinline__ unsigned bf16r(float f) {
    unsigned u = __float_as_uint(f);
    return (u + 0x7fffu + ((u >> 16) & 1u)) >> 16;   // RNE to bf16
}

__global__ void pack_w2_kernel(const float* __restrict__ w2,
                               unsigned* __restrict__ w2pk) {
    int i = blockIdx.x * 256 + threadIdx.x;
    if (i >= 32 * 32 * 16) return;
    int k = i >> 9, d = (i >> 4) & 31, p = i & 15;
    float lo = w2[k * 1024 + d * 32 + 2 * p];
    float hi = w2[k * 1024 + d * 32 + 2 * p + 1];
    w2pk[i] = (bf16r(hi) << 16) | bf16r(lo);
}

// ---------------------------------------------------------------------------
// edge kernel: per edge e
//   h[k]   = relu(b1[k] + sum_d ea[e,d] * w1[d,k])
//   msg[j] = sum_k h[k] * (sum_d x[src,d] * w2[k, d*32+j]) + sum_d x[src,d]*b2[d*32+j]
//   atomicAdd(agg[dst, j], msg[j]);  atomicAdd(cnt[dst], 1)
// 16 lanes per edge; lane ln owns hid 2ln and 2ln+1 (one packed LDS dword -> 2 FMAs)
// ---------------------------------------------------------------------------
__global__ __launch_bounds__(512) void edge_kernel(
    const float* __restrict__ x, const int* __restrict__ ei,
    const float* __restrict__ ea, const float* __restrict__ w1,
    const float* __restrict__ b1, const unsigned* __restrict__ w2pk,
    const float* __restrict__ b2, float* __restrict__ agg,
    float* __restrict__ cnt, int per_block)
{
    __shared__ unsigned sw2[32 * 32 * 16];   // 64 KB, bf16-pair packed w2
    for (int i = threadIdx.x; i < 32 * 32 * 16; i += 512) sw2[i] = w2pk[i];
    __syncthreads();

    const int ln  = threadIdx.x & 15;   // lane within edge group
    const int grp = threadIdx.x >> 4;   // 32 groups per block

    // hoist per-lane constants (reused across all edges)
    const float b1lo = b1[2 * ln], b1hi = b1[2 * ln + 1];
    float w1lo[16], w1hi[16];
    #pragma unroll
    for (int d = 0; d < 16; d++) {
        w1lo[d] = w1[d * 32 + 2 * ln];
        w1hi[d] = w1[d * 32 + 2 * ln + 1];
    }

    int base = blockIdx.x * per_block;
    int end  = base + per_block;
    if (end > NE) end = NE;

    for (int e = base + grp; e < end; e += 32) {
        const int src = ei[e];
        const int dst = ei[NE + e];

        // x[src, 0..31] into registers (broadcast loads within the group)
        float xs[32];
        const float4* x4 = (const float4*)(x + src * 32);
        #pragma unroll
        for (int i = 0; i < 8; i++) {
            float4 v = x4[i];
            xs[4 * i + 0] = v.x; xs[4 * i + 1] = v.y;
            xs[4 * i + 2] = v.z; xs[4 * i + 3] = v.w;
        }

        // h for this lane's two k values
        float h0 = b1lo, h1 = b1hi;
        #pragma unroll
        for (int d = 0; d < 16; d++) {
            float a = ea[e * 16 + d];
            h0 += a * w1lo[d];
            h1 += a * w1hi[d];
        }
        h0 = fmaxf(h0, 0.f);
        h1 = fmaxf(h1, 0.f);

        // main contraction
        float acc0 = 0.f, acc1 = 0.f;
        #pragma unroll 2
        for (int k = 0; k < 32; k++) {
            float hsel = (k & 1) ? h1 : h0;
            float hk = __shfl(hsel, k >> 1, 16);   // owner lane k>>1 within group
            const unsigned* wrow = &sw2[k * 512 + ln];
            float g0 = 0.f, g1 = 0.f;
            #pragma unroll
            for (int d = 0; d < 32; d++) {
                unsigned v = wrow[d * 16];
                float wlo = __uint_as_float(v << 16);
                float whi = __uint_as_float(v & 0xffff0000u);
                g0 += xs[d] * wlo;
                g1 += xs[d] * whi;
            }
            acc0 += hk * g0;
            acc1 += hk * g1;
        }

        // b2 contribution: sum_d x[d] * b2[d*32 + hid]
        #pragma unroll
        for (int d = 0; d < 32; d++) {
            float xv = xs[d];
            acc0 += xv * b2[d * 32 + 2 * ln];
            acc1 += xv * b2[d * 32 + 2 * ln + 1];
        }

        atomicAdd(&agg[dst * 32 + 2 * ln],     acc0);
        atomicAdd(&agg[dst * 32 + 2 * ln + 1], acc1);
        if (ln == 0) atomicAdd(&cnt[dst], 1.0f);
    }
}

// ---------------------------------------------------------------------------
// node kernel (in-place on out, which currently holds agg):
//   m[j]  = agg[n,j]/max(cnt,1) + (x[n]@root)[j] + bias_conv[j]
//   out[n,j] = relu(b3[j] + sum_t x[n,t]*w3[t,j] + sum_t m[t]*w3[32+t,j])
// ---------------------------------------------------------------------------
__global__ __launch_bounds__(256) void node_kernel(
    const float* __restrict__ x, const float* __restrict__ root,
    const float* __restrict__ bias_conv, const float* __restrict__ w3,
    const float* __restrict__ b3, const float* __restrict__ cnt,
    float* __restrict__ out)
{
    __shared__ float xs[8][32];
    __shared__ float ms[8][32];
    const int li = threadIdx.x >> 5, hid = threadIdx.x & 31;
    const int n = blockIdx.x * 8 + li;   // 50000 = 6250*8 exact

    xs[li][hid] = x[n * 32 + hid];
    __syncthreads();

    float xr = 0.f;
    #pragma unroll
    for (int t = 0; t < 32; t++) xr += xs[li][t] * root[t * 32 + hid];

    float c = cnt[n];
    float ic = 1.0f / fmaxf(c, 1.0f);
    float m = out[n * 32 + hid] * ic + xr + bias_conv[hid];
    ms[li][hid] = m;
    __syncthreads();

    float o = b3[hid];
    #pragma unroll
    for (int t = 0; t < 32; t++) {
        o += xs[li][t] * w3[t * 32 + hid];
        o += ms[li][t] * w3[(32 + t) * 32 + hid];
    }
    out[n * 32 + hid] = fmaxf(o, 0.f);
}

// ---------------------------------------------------------------------------
extern "C" void kernel_launch(void* const* d_in, const int* in_sizes, int n_in,
                              void* d_out, int out_size, void* d_ws, size_t ws_size,
                              hipStream_t stream) {
    const float* x    = (const float*)d_in[0];
    const int*   ei   = (const int*)  d_in[1];
    const float* ea   = (const float*)d_in[2];
    const float* w1   = (const float*)d_in[3];
    const float* b1   = (const float*)d_in[4];
    const float* w2   = (const float*)d_in[5];
    const float* b2   = (const float*)d_in[6];
    const float* root = (const float*)d_in[7];
    const float* bc   = (const float*)d_in[8];
    const float* w3   = (const float*)d_in[9];
    const float* b3   = (const float*)d_in[10];

    float*    out  = (float*)d_out;                 // doubles as agg buffer
    float*    cnt  = (float*)d_ws;                  // 50000 f32 = 200000 B
    unsigned* w2pk = (unsigned*)((char*)d_ws + NN * sizeof(float)); // 64 KB

    hipMemsetAsync(d_out, 0, (size_t)NN * NH * sizeof(float), stream);
    hipMemsetAsync(cnt,   0, (size_t)NN * sizeof(float), stream);

    pack_w2_kernel<<<64, 256, 0, stream>>>(w2, w2pk);

    const int nb = 512;
    const int per_block = (NE + nb - 1) / nb;   // 489
    edge_kernel<<<nb, 512, 0, stream>>>(x, ei, ea, w1, b1, w2pk, b2, out, cnt,
                                        per_block);

    node_kernel<<<NN / 8, 256, 0, stream>>>(x, root, bc, w3, b3, cnt, out);
}

// Round 2
// 86.095 us; speedup vs baseline: 7.8883x; 7.8883x over previous
//
#include <hip/hip_runtime.h>

#define NN 50000
#define NE 250000
#define NT 7813   // ceil(NE/32)

typedef __attribute__((ext_vector_type(8)))  short    s16x8;
typedef __attribute__((ext_vector_type(16))) float    f32x16;
typedef __attribute__((ext_vector_type(4)))  unsigned u32x4;

__device__ __forceinline__ unsigned bf16r(float f) {
    unsigned u = __float_as_uint(f);
    return (u + 0x7fffu + ((u >> 16) & 1u)) >> 16;   // RNE
}
__device__ __forceinline__ short bfs(float f) {
    __bf16 b = (__bf16)f;
    return __builtin_bit_cast(short, b);
}

// ---------------------------------------------------------------------------
// w2pk: bf16 B-fragments in LDS image order [66 steps][64 lanes][4 dwords].
// Step s covers rows kk = s*16 .. s*16+16 of w2ext[1056][32]:
//   kk < 1024 : w2ext[kk][hid] = w2[kk>>5][(kk&31)*32 + hid]
//   kk >= 1024: w2ext[kk][hid] = b2[(kk-1024)*32 + hid]     (h == 1 rows)
// Lane l supplies B[s*16 + (l>>5)*8 + j][col = l&31], j = 2q, 2q+1 per dword.
// ---------------------------------------------------------------------------
__global__ void pack_w2(const float* __restrict__ w2, const float* __restrict__ b2,
                        unsigned* __restrict__ w2pk) {
    int i = blockIdx.x * 256 + threadIdx.x;
    if (i >= 66 * 256) return;
    int s = i >> 8, l = (i >> 2) & 63, q = i & 3;
    int col = l & 31;
    int kk = s * 16 + (l >> 5) * 8 + 2 * q;
    float f0 = (kk < 1024) ? w2[(kk >> 5) * 1024 + (kk & 31) * 32 + col]
                           : b2[(kk - 1024) * 32 + col];
    int kk1 = kk + 1;
    float f1 = (kk1 < 1024) ? w2[(kk1 >> 5) * 1024 + (kk1 & 31) * 32 + col]
                            : b2[(kk1 - 1024) * 32 + col];
    w2pk[i] = (bf16r(f1) << 16) | bf16r(f0);
}

// ---------------------------------------------------------------------------
// Edge kernel: per 32-edge tile (one wave):
//   h = relu(ea_tile @ w1 + b1)                (1 MFMA, transposed via LDS)
//   msg_tile = P @ w2ext, P[e, k*32+d] = h[e,k] * x[src(e), d]   (66 MFMA)
//   atomicAdd into agg[dst], atomic count.
// ---------------------------------------------------------------------------
__global__ __launch_bounds__(1024, 4) void edge_kernel(
    const float* __restrict__ x, const int* __restrict__ ei,
    const float* __restrict__ ea, const float* __restrict__ w1,
    const float* __restrict__ b1, const unsigned* __restrict__ w2pk,
    float* __restrict__ agg, float* __restrict__ cnt)
{
    extern __shared__ char smem[];
    unsigned* sw2 = (unsigned*)smem;                       // 67584 B
    {
        u32x4* dstp = (u32x4*)sw2;
        const u32x4* srcp = (const u32x4*)w2pk;
        for (int c = threadIdx.x; c < 66 * 64; c += 1024) dstp[c] = srcp[c];
    }
    __syncthreads();

    const int lane = threadIdx.x & 63;
    const int wave = threadIdx.x >> 6;
    const int er0  = lane & 31;            // A-row edge ; B/D col ; h col
    const int half = lane >> 5;
    float* hl = (float*)(smem + 66 * 1024) + wave * (32 * 33);  // per-wave h

    // B-fragment of w1 (16x32), loaded once: lane l -> w1[(l>>5)*8+j][l&31]
    s16x8 w1f;
    #pragma unroll
    for (int j = 0; j < 8; j++) w1f[j] = bfs(w1[(half * 8 + j) * 32 + er0]);
    const float b1v = b1[er0];

    for (int tile = blockIdx.x * 16 + wave; tile < NT; tile += gridDim.x * 16) {
        const int B0  = tile * 32;
        const int eg  = B0 + er0;
        const int egc = eg < NE ? eg : NE - 1;
        const int src = ei[egc];

        // x[src, d]: this lane only ever needs d in [half*8, half*8+8) and +16
        const float* xp = x + src * 32 + half * 8;
        float4 xa = *(const float4*)xp;
        float4 xb = *(const float4*)(xp + 4);
        float4 xc = *(const float4*)(xp + 16);
        float4 xd = *(const float4*)(xp + 20);
        float xlo[8] = {xa.x, xa.y, xa.z, xa.w, xb.x, xb.y, xb.z, xb.w};
        float xhi[8] = {xc.x, xc.y, xc.z, xc.w, xd.x, xd.y, xd.z, xd.w};

        // A-fragment of ea (32x16): lane l -> ea[e=l&31][(l>>5)*8+j]
        const float* epp = ea + (size_t)egc * 16 + half * 8;
        float4 e0 = *(const float4*)epp;
        float4 e1 = *(const float4*)(epp + 4);
        s16x8 eaf;
        eaf[0]=bfs(e0.x); eaf[1]=bfs(e0.y); eaf[2]=bfs(e0.z); eaf[3]=bfs(e0.w);
        eaf[4]=bfs(e1.x); eaf[5]=bfs(e1.y); eaf[6]=bfs(e1.z); eaf[7]=bfs(e1.w);

        // h = relu(ea @ w1 + b1); C/D: row=(r&3)+8*(r>>2)+4*(lane>>5), col=lane&31
        f32x16 hc = {};
        hc = __builtin_amdgcn_mfma_f32_32x32x16_bf16(eaf, w1f, hc, 0, 0, 0);
        #pragma unroll
        for (int r = 0; r < 16; r++) {
            int e = (r & 3) + 8 * (r >> 2) + 4 * half;
            hl[e * 33 + er0] = fmaxf(hc[r] + b1v, 0.f);
        }

        // main GEMM: 66 K-steps of 16 (64 = h x w2, 2 = b2 rows with h == 1)
        f32x16 acc = {};
        const float* hrow = hl + er0 * 33;
        #pragma unroll
        for (int s2 = 0; s2 < 32; s2++) {
            float hk = hrow[s2];
            s16x8 alo, ahi;
            #pragma unroll
            for (int j = 0; j < 8; j++) alo[j] = bfs(hk * xlo[j]);
            #pragma unroll
            for (int j = 0; j < 8; j++) ahi[j] = bfs(hk * xhi[j]);
            s16x8 blo = *(const s16x8*)(sw2 + (2 * s2)     * 256 + lane * 4);
            s16x8 bhi = *(const s16x8*)(sw2 + (2 * s2 + 1) * 256 + lane * 4);
            acc = __builtin_amdgcn_mfma_f32_32x32x16_bf16(alo, blo, acc, 0, 0, 0);
            acc = __builtin_amdgcn_mfma_f32_32x32x16_bf16(ahi, bhi, acc, 0, 0, 0);
        }
        {
            s16x8 alo, ahi;
            #pragma unroll
            for (int j = 0; j < 8; j++) alo[j] = bfs(xlo[j]);
            #pragma unroll
            for (int j = 0; j < 8; j++) ahi[j] = bfs(xhi[j]);
            s16x8 b64 = *(const s16x8*)(sw2 + 64 * 256 + lane * 4);
            s16x8 b65 = *(const s16x8*)(sw2 + 65 * 256 + lane * 4);
            acc = __builtin_amdgcn_mfma_f32_32x32x16_bf16(alo, b64, acc, 0, 0, 0);
            acc = __builtin_amdgcn_mfma_f32_32x32x16_bf16(ahi, b65, acc, 0, 0, 0);
        }

        // scatter: D row = edge, col = hid = lane&31
        #pragma unroll
        for (int r = 0; r < 16; r++) {
            int e  = (r & 3) + 8 * (r >> 2) + 4 * half;
            int ge = B0 + e;
            if (ge < NE) {
                int d = ei[NE + ge];
                atomicAdd(&agg[d * 32 + er0], acc[r]);
            }
        }
        if (lane < 32 && eg < NE) atomicAdd(&cnt[ei[NE + eg]], 1.0f);
    }
}

// ---------------------------------------------------------------------------
// node kernel (in-place on out, which currently holds agg) — same as round 1
// ---------------------------------------------------------------------------
__global__ __launch_bounds__(256) void node_kernel(
    const float* __restrict__ x, const float* __restrict__ root,
    const float* __restrict__ bias_conv, const float* __restrict__ w3,
    const float* __restrict__ b3, const float* __restrict__ cnt,
    float* __restrict__ out)
{
    __shared__ float xs[8][32];
    __shared__ float ms[8][32];
    const int li = threadIdx.x >> 5, hid = threadIdx.x & 31;
    const int n = blockIdx.x * 8 + li;

    xs[li][hid] = x[n * 32 + hid];
    __syncthreads();

    float xr = 0.f;
    #pragma unroll
    for (int t = 0; t < 32; t++) xr += xs[li][t] * root[t * 32 + hid];

    float c = cnt[n];
    float ic = 1.0f / fmaxf(c, 1.0f);
    float m = out[n * 32 + hid] * ic + xr + bias_conv[hid];
    ms[li][hid] = m;
    __syncthreads();

    float o = b3[hid];
    #pragma unroll
    for (int t = 0; t < 32; t++) {
        o += xs[li][t] * w3[t * 32 + hid];
        o += ms[li][t] * w3[(32 + t) * 32 + hid];
    }
    out[n * 32 + hid] = fmaxf(o, 0.f);
}

// ---------------------------------------------------------------------------
extern "C" void kernel_launch(void* const* d_in, const int* in_sizes, int n_in,
                              void* d_out, int out_size, void* d_ws, size_t ws_size,
                              hipStream_t stream) {
    const float* x    = (const float*)d_in[0];
    const int*   ei   = (const int*)  d_in[1];
    const float* ea   = (const float*)d_in[2];
    const float* w1   = (const float*)d_in[3];
    const float* b1   = (const float*)d_in[4];
    const float* w2   = (const float*)d_in[5];
    const float* b2   = (const float*)d_in[6];
    const float* root = (const float*)d_in[7];
    const float* bc   = (const float*)d_in[8];
    const float* w3   = (const float*)d_in[9];
    const float* b3   = (const float*)d_in[10];

    float*    out  = (float*)d_out;                         // doubles as agg
    float*    cnt  = (float*)d_ws;                          // 200000 B
    unsigned* w2pk = (unsigned*)((char*)d_ws + NN * sizeof(float)); // 67584 B

    hipMemsetAsync(d_out, 0, (size_t)NN * 32 * sizeof(float), stream);
    hipMemsetAsync(cnt,   0, (size_t)NN * sizeof(float), stream);

    pack_w2<<<66, 256, 0, stream>>>(w2, b2, w2pk);

    const int lds_bytes = 66 * 1024 + 16 * 32 * 33 * 4;     // 135168
    hipFuncSetAttribute((const void*)edge_kernel,
                        hipFuncAttributeMaxDynamicSharedMemorySize, lds_bytes);
    edge_kernel<<<256, 1024, lds_bytes, stream>>>(x, ei, ea, w1, b1, w2pk, out, cnt);

    node_kernel<<<NN / 8, 256, 0, stream>>>(x, root, bc, w3, b3, cnt, out);
}